// Round 7
// baseline (991.702 us; speedup 1.0000x reference)
//
#include <hip/hip_runtime.h>
#include <cstdint>

// MoE grouped-GEMM pipeline for MI355X (gfx950).
//   T=4096 tokens, D=1024, H=5632, experts 0..3 active (4..7 masked), top-2.
// R9 == R8 resubmit (GPU unavailable; re-audited vmcnt ledger, cross-wave
//     visibility, WAR race, geometry -- no changes).
// R8: m201-class 8-phase schedule. Block 256x128, 8 waves (4m x 2n), wave 64x64,
//     BK=64, double-buffered half-tile-staged LDS, per-phase
//     {ds_read || stage-issue || bar || lgkm0 || setprio MFMA || bar},
//     counted vmcnt (vm4/vm3, never 0 mid-loop). gemm1 dual-B holds A-frags in
//     regs across matrix phases. R5/R6 measured 35% MfmaUtil at the 2-barrier
//     structure regardless of occupancy -> structure, not occupancy, is the wall.
// Workspace layout (bytes), total 240,681,024 (yb aliases w1b, dead after gemm1):
//   xb 0 | w1b/yb 8388608 | w3b 54525952 | w2b 100663296 | hb 146800640 (8320 rows pad)
//   cnt 240517120 | offs 240517152 | perm 240517184 | wgt 240582720 | code 240648256

#define T_TOK 4096
#define DIM   1024
#define HID   5632
#define EA    4
#define NT1   16     // gemm1 K-tiles: 1024/64
#define NT2   88     // gemm2 K-tiles: 5632/64

typedef __bf16 bf16x8 __attribute__((ext_vector_type(8)));
typedef float  f32x4  __attribute__((ext_vector_type(4)));

__device__ __forceinline__ unsigned short f2b(float f) {
  union { float f; uint32_t u; } v; v.f = f;
  uint32_t r = v.u + 0x7fffu + ((v.u >> 16) & 1u);   // RNE, matches HW cvt
  return (unsigned short)(r >> 16);
}
__device__ __forceinline__ float b2f(unsigned short u) {
  union { uint32_t u; float f; } v; v.u = ((uint32_t)u) << 16;
  return v.f;
}
// async global->LDS, 16B per lane; LDS dest = wave-uniform base + lane*16
__device__ __forceinline__ void async16(const void* g, void* l) {
  __builtin_amdgcn_global_load_lds((const __attribute__((address_space(1))) void*)g,
                                   (__attribute__((address_space(3))) void*)l,
                                   16, 0, 0);
}
// raw sync primitives: keep prefetch loads in flight across the barrier
__device__ __forceinline__ void bar_raw()   { asm volatile("s_barrier" ::: "memory"); }
__device__ __forceinline__ void wait_vm4()  { asm volatile("s_waitcnt vmcnt(4)" ::: "memory"); }
__device__ __forceinline__ void wait_vm3()  { asm volatile("s_waitcnt vmcnt(3)" ::: "memory"); }
__device__ __forceinline__ void wait_vm0()  { asm volatile("s_waitcnt vmcnt(0)" ::: "memory"); }
__device__ __forceinline__ void wait_lgkm0(){ asm volatile("s_waitcnt lgkmcnt(0)" ::: "memory"); }

// LDS tile swizzle: logical byte L in a [rows][32 bf16] region (64B rows),
// phys = L ^ ((row&7)<<4)  with row = L>>6, i.e. p4^=L6, p5^=L7, p6^=L8.
// Read side: frag offset ^= (lane&7)<<4 (row bits 0-2 == fm bits 0-2).
// Stage side uses the inverse (phys slot -> logical element); 16B-block-preserving.
__device__ __forceinline__ int inv_swz(int p) {
  const int b6 = (p >> 6) & 1, b7 = (p >> 7) & 1, b8 = (p >> 8) & 1;
  return p ^ (((b6 ^ b8) << 4) | (b7 << 5) | (b8 << 6));
}

// ---------------- x fp32 -> bf16 ----------------
__global__ void cvtx_kernel(const float* __restrict__ x, unsigned short* __restrict__ xb) {
  const int i = blockIdx.x * blockDim.x + threadIdx.x;
  const float4 v = ((const float4*)x)[i];
  ushort4 o;
  o.x = f2b(v.x); o.y = f2b(v.y); o.z = f2b(v.z); o.w = f2b(v.w);
  ((ushort4*)xb)[i] = o;
}

// ---------------- gating: fp32 logits (experts 0..3), top-2, route ----------------
__global__ void gate_kernel(const float* __restrict__ x, const float* __restrict__ gw,
                            int* __restrict__ cnt, int* __restrict__ perm,
                            float* __restrict__ wgt, int* __restrict__ code) {
  const int lane = threadIdx.x & 63;
  const int wave = threadIdx.x >> 6;
  const int t = blockIdx.x * 4 + wave;          // one wave per token
  const float4* xv = (const float4*)(x + (size_t)t * DIM);
  const float4* g0 = (const float4*)gw;
  const float4* g1 = (const float4*)(gw + DIM);
  const float4* g2 = (const float4*)(gw + 2 * DIM);
  const float4* g3 = (const float4*)(gw + 3 * DIM);
  float a0 = 0.f, a1 = 0.f, a2 = 0.f, a3 = 0.f;
#pragma unroll
  for (int i = 0; i < 4; i++) {
    const int idx = i * 64 + lane;
    const float4 v = xv[idx];
    float4 w;
    w = g0[idx]; a0 += v.x*w.x + v.y*w.y + v.z*w.z + v.w*w.w;
    w = g1[idx]; a1 += v.x*w.x + v.y*w.y + v.z*w.z + v.w*w.w;
    w = g2[idx]; a2 += v.x*w.x + v.y*w.y + v.z*w.z + v.w*w.w;
    w = g3[idx]; a3 += v.x*w.x + v.y*w.y + v.z*w.z + v.w*w.w;
  }
#pragma unroll
  for (int off = 32; off > 0; off >>= 1) {
    a0 += __shfl_xor(a0, off);
    a1 += __shfl_xor(a1, off);
    a2 += __shfl_xor(a2, off);
    a3 += __shfl_xor(a3, off);
  }
  if (lane == 0) {
    float l[4] = {a0, a1, a2, a3};
    int a = 0;
#pragma unroll
    for (int e = 1; e < 4; e++) if (l[e] > l[a]) a = e;   // ties -> lower index (jax top_k)
    int b = (a == 0) ? 1 : 0;
#pragma unroll
    for (int e = 0; e < 4; e++) if (e != a && l[e] > l[b]) b = e;
    // softmax(top2) renormalized == sigmoid of logit gap
    const float wa = 1.0f / (1.0f + __expf(l[b] - l[a]));
    const float wb = 1.0f - wa;
    const int pa = atomicAdd(&cnt[a], 1);
    const int pb = atomicAdd(&cnt[b], 1);
    perm[a * T_TOK + pa] = t;  wgt[a * T_TOK + pa] = wa;  code[t * 2 + 0] = a * T_TOK + pa;
    perm[b * T_TOK + pb] = t;  wgt[b * T_TOK + pb] = wb;  code[t * 2 + 1] = b * T_TOK + pb;
  }
}

__global__ void offsets_kernel(const int* __restrict__ cnt, int* __restrict__ offs) {
  if (threadIdx.x == 0 && blockIdx.x == 0) {
    int s = 0;
#pragma unroll
    for (int e = 0; e < EA; e++) { offs[e] = s; s += cnt[e]; }
  }
}

// ---------------- per-expert transpose + fp32->bf16: in [R][C] -> out [C][R] ----------------
__global__ void tcvt_kernel(const float* __restrict__ in, unsigned short* __restrict__ out,
                            int R, int C) {
  __shared__ float tile[64][65];
  const size_t es = (size_t)R * C;
  const float* ip = in + (size_t)blockIdx.z * es;
  unsigned short* op = out + (size_t)blockIdx.z * es;
  const int bc = blockIdx.x * 64;
  const int br = blockIdx.y * 64;
  const int tr = threadIdx.x >> 4;
  const int tc = (threadIdx.x & 15) * 4;
#pragma unroll
  for (int i = 0; i < 4; i++) {
    const float4 v = *(const float4*)(ip + (size_t)(br + tr + i * 16) * C + bc + tc);
    tile[tr + i * 16][tc + 0] = v.x;
    tile[tr + i * 16][tc + 1] = v.y;
    tile[tr + i * 16][tc + 2] = v.z;
    tile[tr + i * 16][tc + 3] = v.w;
  }
  __syncthreads();
#pragma unroll
  for (int i = 0; i < 4; i++) {
    const int n = bc + tr + i * 16;
    ushort4 o;
    o.x = f2b(tile[tc + 0][tr + i * 16]);
    o.y = f2b(tile[tc + 1][tr + i * 16]);
    o.z = f2b(tile[tc + 2][tr + i * 16]);
    o.w = f2b(tile[tc + 3][tr + i * 16]);
    *(ushort4*)(op + (size_t)n * R + br + tc) = o;
  }
}

// ---------------- GEMM1: h = silu(x@w1) * (x@w3) ----------------
// Block 256M x 128N, 8 waves (4wm x 2wn), wave 64x64 per matrix, BK=64.
// LDS 2 bufs x 64KB: Ak0 16K@0 | Ak1 16K@16384 | B1k0 8K@32768 | B1k1 8K@40960
//                    | B3k0 8K@49152 | B3k1 8K@57344. 64B rows, XOR-swizzled.
// 4 phases/kt: {Ak0+B1k0 -> acc1}{B3k0 -> acc3, vm4}{Ak1+B1k1 -> acc1}{B3k1 -> acc3, vm4}
// Half-tile staging (h0 = k-lo 4 loads, h1 = k-hi 4 loads), vmcnt never 0 mid-loop.
// Grid 2816: nb fastest (44), e (4), mb (16); same-(e,nb) stride 176 % 8 == 0.
__global__ __launch_bounds__(512, 2)
void gemm1_kernel(const unsigned short* __restrict__ xb,
                  const unsigned short* __restrict__ w1b,
                  const unsigned short* __restrict__ w3b,
                  unsigned short* __restrict__ hb,
                  const int* __restrict__ cnt, const int* __restrict__ offs,
                  const int* __restrict__ perm) {
  const int id = blockIdx.x;
  const int nb = id % 44;
  const int e  = (id / 44) % 4;
  const int mb = id / 176;              // 0..15
  const int Me = cnt[e];
  const int m0 = mb * 256;
  if (m0 >= Me) return;
  const int n0 = nb * 128;
  const int goff = offs[e];
  const int tid = threadIdx.x, lane = tid & 63, wave = tid >> 6;
  const int wm = wave >> 1, wn = wave & 1;
  const int fm = lane & 15;

  __shared__ __align__(16) char smem[2 * 65536];

  // ---- staging map: thread t writes phys region bytes [t*16, t*16+16) per batch.
  // 512 thr x 16B = 8KB batch = 128 rows of 64B. srow/scol via inv_swz.
  const int t16 = tid * 16;
  const int l0 = inv_swz(t16);
  const int srow = l0 >> 6;             // 0..127
  const int ks   = (l0 & 63) >> 1;      // shorts within 32-short k-slice
  const int tok0 = perm[e * T_TOK + min(m0 + srow, Me - 1)];
  const int tok1 = perm[e * T_TOK + min(m0 + 128 + srow, Me - 1)];
  const unsigned short* ap0 = xb + (size_t)tok0 * DIM + ks;
  const unsigned short* ap1 = xb + (size_t)tok1 * DIM + ks;
  const unsigned short* b1p = w1b + ((size_t)e * HID + n0 + srow) * DIM + ks;
  const unsigned short* b3p = w3b + ((size_t)e * HID + n0 + srow) * DIM + ks;

  // ---- LDS stage dests (wave-uniform; HW adds lane*16)
  const int dA0 = wave * 1024;                 // Ak0 batch0; batch1 at +8192; Ak1 at +16384
  const int dA1 = 8192  + wave * 1024;
  const int dB1 = 32768 + wave * 1024;         // B1k0; B1k1 at +8192
  const int dB3 = 49152 + wave * 1024;         // B3k0; B3k1 at +8192

  // ---- swizzled frag read offsets (row = w*64 + f_i*16 + fm; row&7 == lane&7)
  const int X = (lane & 7) << 4;
  const int aoff = (((wm * 64 + fm) * 64) + ((lane >> 4) * 16)) ^ X;
  const int boff = (((wn * 64 + fm) * 64) + ((lane >> 4) * 16)) ^ X;

  f32x4 acc1[4][4] = {};
  f32x4 acc3[4][4] = {};

  // ---- prologue: stage kt0 h0+h1 into buf0 (8 loads/thread in flight)
  {
    char* D = smem;
    async16(ap0, D + dA0);            async16(ap1, D + dA1);
    async16(b1p, D + dB1);            async16(b3p, D + dB3);
    async16(ap0 + 32, D + dA0 + 16384); async16(ap1 + 32, D + dA1 + 16384);
    async16(b1p + 32, D + dB1 + 8192);  async16(b3p + 32, D + dB3 + 8192);
    ap0 += 64; ap1 += 64; b1p += 64; b3p += 64;
  }
  wait_vm4();               // kt0 h0 landed; h1 (4 loads) still in flight
  bar_raw();

  for (int kt = 0; kt < NT1; ++kt) {
    const char* S = smem + (kt & 1) * 65536;
    char* D = smem + ((kt + 1) & 1) * 65536;
    const bool nl = (kt < NT1 - 1);
    bf16x8 af[4], bfr[4];
    // ===== ph0: read Ak0 + B1k0, stage kt+1 A-k0, MFMA acc1 =====
#pragma unroll
    for (int mi = 0; mi < 4; mi++)
      af[mi] = *(const bf16x8*)(S + aoff + mi * 1024);
#pragma unroll
    for (int ni = 0; ni < 4; ni++)
      bfr[ni] = *(const bf16x8*)(S + 32768 + boff + ni * 1024);
    if (nl) { async16(ap0, D + dA0); async16(ap1, D + dA1); }
    bar_raw(); wait_lgkm0();
    __builtin_amdgcn_s_setprio(1);
#pragma unroll
    for (int mi = 0; mi < 4; mi++)
#pragma unroll
      for (int ni = 0; ni < 4; ni++)
        acc1[mi][ni] = __builtin_amdgcn_mfma_f32_16x16x32_bf16(af[mi], bfr[ni], acc1[mi][ni], 0, 0, 0);
    __builtin_amdgcn_s_setprio(0);
    bar_raw();
    // ===== ph1: read B3k0 (A regs reused), stage kt+1 B-k0, vm4, MFMA acc3 =====
#pragma unroll
    for (int ni = 0; ni < 4; ni++)
      bfr[ni] = *(const bf16x8*)(S + 49152 + boff + ni * 1024);
    if (nl) { async16(b1p, D + dB1); async16(b3p, D + dB3); wait_vm4(); }
    else    { wait_vm0(); }
    bar_raw(); wait_lgkm0();
    __builtin_amdgcn_s_setprio(1);
#pragma unroll
    for (int mi = 0; mi < 4; mi++)
#pragma unroll
      for (int ni = 0; ni < 4; ni++)
        acc3[mi][ni] = __builtin_amdgcn_mfma_f32_16x16x32_bf16(af[mi], bfr[ni], acc3[mi][ni], 0, 0, 0);
    __builtin_amdgcn_s_setprio(0);
    bar_raw();
    // ===== ph2: read Ak1 + B1k1, stage kt+1 A-k1, MFMA acc1 =====
#pragma unroll
    for (int mi = 0; mi < 4; mi++)
      af[mi] = *(const bf16x8*)(S + 16384 + aoff + mi * 1024);
#pragma unroll
    for (int ni = 0; ni < 4; ni++)
      bfr[ni] = *(const bf16x8*)(S + 40960 + boff + ni * 1024);
    if (nl) { async16(ap0 + 32, D + dA0 + 16384); async16(ap1 + 32, D + dA1 + 16384); }
    bar_raw(); wait_lgkm0();
    __builtin_amdgcn_s_setprio(1);
#pragma unroll
    for (int mi = 0; mi < 4; mi++)
#pragma unroll
      for (int ni = 0; ni < 4; ni++)
        acc1[mi][ni] = __builtin_amdgcn_mfma_f32_16x16x32_bf16(af[mi], bfr[ni], acc1[mi][ni], 0, 0, 0);
    __builtin_amdgcn_s_setprio(0);
    bar_raw();
    // ===== ph3: read B3k1, stage kt+1 B-k1, vm4, MFMA acc3 =====
#pragma unroll
    for (int ni = 0; ni < 4; ni++)
      bfr[ni] = *(const bf16x8*)(S + 57344 + boff + ni * 1024);
    if (nl) {
      async16(b1p + 32, D + dB1 + 8192); async16(b3p + 32, D + dB3 + 8192);
      ap0 += 64; ap1 += 64; b1p += 64; b3p += 64;
      wait_vm4();
    } else { wait_vm0(); }
    bar_raw(); wait_lgkm0();
    __builtin_amdgcn_s_setprio(1);
#pragma unroll
    for (int mi = 0; mi < 4; mi++)
#pragma unroll
      for (int ni = 0; ni < 4; ni++)
        acc3[mi][ni] = __builtin_amdgcn_mfma_f32_16x16x32_bf16(af[mi], bfr[ni], acc3[mi][ni], 0, 0, 0);
    __builtin_amdgcn_s_setprio(0);
    bar_raw();
  }

  // ---- epilogue: SwiGLU, masked store (C/D layout: col=lane&15, row=(lane>>4)*4+reg)
#pragma unroll
  for (int mi = 0; mi < 4; mi++) {
#pragma unroll
    for (int r = 0; r < 4; r++) {
      const int m = m0 + wm * 64 + mi * 16 + (lane >> 4) * 4 + r;
      if (m < Me) {
        unsigned short* hp = hb + (size_t)(goff + m) * HID + n0 + wn * 64 + fm;
#pragma unroll
        for (int ni = 0; ni < 4; ni++) {
          const float a = acc1[mi][ni][r];
          const float g = acc3[mi][ni][r];
          hp[ni * 16] = f2b((a / (1.0f + __expf(-a))) * g);
        }
      }
    }
  }
}

// ---------------- GEMM2: y = (h @ w2) * gate_w ----------------
// Block 256M x 128N, 8 waves (4wm x 2wn), wave 64x64, BK=64.
// LDS 2 bufs x 48KB: Ak0 16K@0 | Ak1 16K@16384 | Bk0 8K@32768 | Bk1 8K@40960.
// 2 phases/kt: {Ak0+Bk0}{Ak1+Bk1}, half staging 3 loads/phase, vm3 counted.
// Grid 512: nb fastest (8), e (4), mb (16); same-(e,nb) stride 32 % 8 == 0.
__global__ __launch_bounds__(512, 2)
void gemm2_kernel(const unsigned short* __restrict__ hb,
                  const unsigned short* __restrict__ w2b,
                  unsigned short* __restrict__ yb,
                  const int* __restrict__ cnt, const int* __restrict__ offs,
                  const float* __restrict__ wgt) {
  const int id = blockIdx.x;
  const int nb = id & 7;
  const int e  = (id >> 3) & 3;
  const int mb = id >> 5;               // 0..15
  const int Me = cnt[e];
  const int m0 = mb * 256;
  if (m0 >= Me) return;
  const int n0 = nb * 128;
  const int goff = offs[e];
  const int tid = threadIdx.x, lane = tid & 63, wave = tid >> 6;
  const int wm = wave >> 1, wn = wave & 1;
  const int fm = lane & 15;

  __shared__ __align__(16) char smem[2 * 49152];

  const int t16 = tid * 16;
  const int l0 = inv_swz(t16);
  const int srow = l0 >> 6;             // 0..127
  const int ks   = (l0 & 63) >> 1;
  const unsigned short* ap0 = hb + (size_t)(goff + min(m0 + srow, Me - 1)) * HID + ks;
  const unsigned short* ap1 = hb + (size_t)(goff + min(m0 + 128 + srow, Me - 1)) * HID + ks;
  const unsigned short* bp  = w2b + ((size_t)e * DIM + n0 + srow) * HID + ks;

  const int dA0 = wave * 1024;                 // Ak0 b0; b1 +8192; Ak1 +16384
  const int dA1 = 8192  + wave * 1024;
  const int dB  = 32768 + wave * 1024;         // Bk0; Bk1 +8192

  const int X = (lane & 7) << 4;
  const int aoff = (((wm * 64 + fm) * 64) + ((lane >> 4) * 16)) ^ X;
  const int boff = (((wn * 64 + fm) * 64) + ((lane >> 4) * 16)) ^ X;

  f32x4 acc[4][4] = {};

  // prologue: stage kt0 h0+h1 into buf0 (6 loads in flight)
  {
    char* D = smem;
    async16(ap0, D + dA0); async16(ap1, D + dA1); async16(bp, D + dB);
    async16(ap0 + 32, D + dA0 + 16384); async16(ap1 + 32, D + dA1 + 16384); async16(bp + 32, D + dB + 8192);
    ap0 += 64; ap1 += 64; bp += 64;
  }
  wait_vm3();               // kt0 h0 landed; h1 (3) in flight
  bar_raw();

  for (int kt = 0; kt < NT2; ++kt) {
    const char* S = smem + (kt & 1) * 49152;
    char* D = smem + ((kt + 1) & 1) * 49152;
    const bool nl = (kt < NT2 - 1);
    bf16x8 af[4], bfr[4];
    // ===== ph0: Ak0 + Bk0, stage kt+1 h0, vm3, MFMA =====
#pragma unroll
    for (int mi = 0; mi < 4; mi++)
      af[mi] = *(const bf16x8*)(S + aoff + mi * 1024);
#pragma unroll
    for (int ni = 0; ni < 4; ni++)
      bfr[ni] = *(const bf16x8*)(S + 32768 + boff + ni * 1024);
    if (nl) { async16(ap0, D + dA0); async16(ap1, D + dA1); async16(bp, D + dB); wait_vm3(); }
    else    { wait_vm0(); }
    bar_raw(); wait_lgkm0();
    __builtin_amdgcn_s_setprio(1);
#pragma unroll
    for (int mi = 0; mi < 4; mi++)
#pragma unroll
      for (int ni = 0; ni < 4; ni++)
        acc[mi][ni] = __builtin_amdgcn_mfma_f32_16x16x32_bf16(af[mi], bfr[ni], acc[mi][ni], 0, 0, 0);
    __builtin_amdgcn_s_setprio(0);
    bar_raw();
    // ===== ph1: Ak1 + Bk1, stage kt+1 h1, vm3, MFMA =====
#pragma unroll
    for (int mi = 0; mi < 4; mi++)
      af[mi] = *(const bf16x8*)(S + 16384 + aoff + mi * 1024);
#pragma unroll
    for (int ni = 0; ni < 4; ni++)
      bfr[ni] = *(const bf16x8*)(S + 40960 + boff + ni * 1024);
    if (nl) {
      async16(ap0 + 32, D + dA0 + 16384); async16(ap1 + 32, D + dA1 + 16384); async16(bp + 32, D + dB + 8192);
      ap0 += 64; ap1 += 64; bp += 64;
      wait_vm3();
    } else { wait_vm0(); }
    bar_raw(); wait_lgkm0();
    __builtin_amdgcn_s_setprio(1);
#pragma unroll
    for (int mi = 0; mi < 4; mi++)
#pragma unroll
      for (int ni = 0; ni < 4; ni++)
        acc[mi][ni] = __builtin_amdgcn_mfma_f32_16x16x32_bf16(af[mi], bfr[ni], acc[mi][ni], 0, 0, 0);
    __builtin_amdgcn_s_setprio(0);
    bar_raw();
  }

#pragma unroll
  for (int mi = 0; mi < 4; mi++) {
#pragma unroll
    for (int r = 0; r < 4; r++) {
      const int m = m0 + wm * 64 + mi * 16 + (lane >> 4) * 4 + r;
      if (m < Me) {
        const float gwv = wgt[e * T_TOK + m];
        unsigned short* yp = yb + (size_t)(goff + m) * DIM + n0 + wn * 64 + fm;
#pragma unroll
        for (int ni = 0; ni < 4; ni++)
          yp[ni * 16] = f2b(acc[mi][ni][r] * gwv);
      }
    }
  }
}

// ---------------- combine: out[t] = y[slot0(t)] + y[slot1(t)] ----------------
__global__ void combine_kernel(const unsigned short* __restrict__ yb,
                               const int* __restrict__ code,
                               const int* __restrict__ offs,
                               float* __restrict__ out) {
  const int t = blockIdx.x;
  const int d = threadIdx.x * 4;
  const int c0 = code[t * 2 + 0];
  const int c1 = code[t * 2 + 1];
  const size_t g0 = ((size_t)(offs[c0 >> 12] + (c0 & 4095))) * DIM + d;
  const size_t g1 = ((size_t)(offs[c1 >> 12] + (c1 & 4095))) * DIM + d;
  const ushort4 y0 = *(const ushort4*)(yb + g0);
  const ushort4 y1 = *(const ushort4*)(yb + g1);
  float4 o;
  o.x = b2f(y0.x) + b2f(y1.x);
  o.y = b2f(y0.y) + b2f(y1.y);
  o.z = b2f(y0.z) + b2f(y1.z);
  o.w = b2f(y0.w) + b2f(y1.w);
  *(float4*)(out + (size_t)t * DIM + d) = o;
}

extern "C" void kernel_launch(void* const* d_in, const int* in_sizes, int n_in,
                              void* d_out, int out_size, void* d_ws, size_t ws_size,
                              hipStream_t stream) {
  (void)in_sizes; (void)n_in; (void)out_size; (void)ws_size;
  const float* x  = (const float*)d_in[0];
  const float* gw = (const float*)d_in[1];
  const float* w1 = (const float*)d_in[2];   // [E][D][H]
  const float* w2 = (const float*)d_in[3];   // [E][H][D]  (dict order: w2 before w3!)
  const float* w3 = (const float*)d_in[4];   // [E][D][H]
  float* out = (float*)d_out;
  char* ws = (char*)d_ws;

  unsigned short* xb  = (unsigned short*)(ws + 0);
  unsigned short* w1b = (unsigned short*)(ws + 8388608);
  unsigned short* yb  = (unsigned short*)(ws + 8388608);    // aliases w1b (dead after gemm1)
  unsigned short* w3b = (unsigned short*)(ws + 54525952);
  unsigned short* w2b = (unsigned short*)(ws + 100663296);
  unsigned short* hb  = (unsigned short*)(ws + 146800640);  // 8320 rows x 5632 bf16 (128 pad rows)
  int*   cnt  = (int*)(ws + 240517120);
  int*   offs = (int*)(ws + 240517152);
  int*   perm = (int*)(ws + 240517184);
  float* wgt  = (float*)(ws + 240582720);
  int*   code = (int*)(ws + 240648256);

  hipMemsetAsync(cnt, 0, EA * sizeof(int), stream);
  cvtx_kernel<<<4096, 256, 0, stream>>>(x, xb);
  gate_kernel<<<1024, 256, 0, stream>>>(x, gw, cnt, perm, wgt, code);
  offsets_kernel<<<1, 64, 0, stream>>>(cnt, offs);
  tcvt_kernel<<<dim3(88, 16, EA), 256, 0, stream>>>(w1, w1b, DIM, HID);  // -> [e][H][D]
  tcvt_kernel<<<dim3(88, 16, EA), 256, 0, stream>>>(w3, w3b, DIM, HID);  // -> [e][H][D]
  tcvt_kernel<<<dim3(16, 88, EA), 256, 0, stream>>>(w2, w2b, HID, DIM);  // -> [e][D][H]
  gemm1_kernel<<<2816, 512, 0, stream>>>(xb, w1b, w3b, hb, cnt, offs, perm);
  gemm2_kernel<<<512, 512, 0, stream>>>(hb, w2b, yb, cnt, offs, wgt);
  combine_kernel<<<4096, 256, 0, stream>>>(yb, code, offs, out);
}

// Round 12
// 939.293 us; speedup vs baseline: 1.0558x; 1.0558x over previous
//
#include <hip/hip_runtime.h>
#include <cstdint>

// MoE grouped-GEMM pipeline for MI355X (gfx950).
//   T=4096 tokens, D=1024, H=5632, experts 0..3 active (4..7 masked), top-2.
// R14 == R10 resubmit x4 (GPU unavailable 4 consecutive rounds for this config).
//     Only never-benched code is the tcvt store phase; its proofs stand:
//     bijective tile coverage, 2-way-free LDS reads, 128B-contiguous stores.
// R10: gemm1 = R9 (best measured, 234us). gemm2 = R6 revert (48KB, 3 blk/CU --
//     R9's 96KB variant was ~48us slower). tcvt rewritten with 16B ushort8
//     stores (old path: 64 scattered 8B txns/wave -> ~10x decoalesced, the
//     likely >=473us non-gemm pool).
// Workspace layout (bytes), total 240,681,024 (yb aliases w1b, dead after gemm1):
//   xb 0 | w1b/yb 8388608 | w3b 54525952 | w2b 100663296 | hb 146800640 (8320 rows pad)
//   cnt 240517120 | offs 240517152 | perm 240517184 | wgt 240582720 | code 240648256

#define T_TOK 4096
#define DIM   1024
#define HID   5632
#define EA    4
#define NT1   16     // gemm1 K-tiles: 1024/64
#define NT2G  176    // gemm2 K-tiles: 5632/32

typedef __bf16 bf16x8 __attribute__((ext_vector_type(8)));
typedef float  f32x4  __attribute__((ext_vector_type(4)));
typedef unsigned short ushort8 __attribute__((ext_vector_type(8)));

__device__ __forceinline__ unsigned short f2b(float f) {
  union { float f; uint32_t u; } v; v.f = f;
  uint32_t r = v.u + 0x7fffu + ((v.u >> 16) & 1u);   // RNE, matches HW cvt
  return (unsigned short)(r >> 16);
}
__device__ __forceinline__ float b2f(unsigned short u) {
  union { uint32_t u; float f; } v; v.u = ((uint32_t)u) << 16;
  return v.f;
}
// async global->LDS, 16B per lane; LDS dest = wave-uniform base + lane*16
__device__ __forceinline__ void async16(const void* g, void* l) {
  __builtin_amdgcn_global_load_lds((const __attribute__((address_space(1))) void*)g,
                                   (__attribute__((address_space(3))) void*)l,
                                   16, 0, 0);
}
// raw sync primitives: keep prefetch loads in flight across the barrier
__device__ __forceinline__ void bar_raw()   { asm volatile("s_barrier" ::: "memory"); }
__device__ __forceinline__ void wait_vm6()  { asm volatile("s_waitcnt vmcnt(6)" ::: "memory"); }
__device__ __forceinline__ void wait_vm4()  { asm volatile("s_waitcnt vmcnt(4)" ::: "memory"); }
__device__ __forceinline__ void wait_vm0()  { asm volatile("s_waitcnt vmcnt(0)" ::: "memory"); }
__device__ __forceinline__ void wait_lgkm0(){ asm volatile("s_waitcnt lgkmcnt(0)" ::: "memory"); }

// LDS tile swizzle: logical byte L in a [rows][32 bf16] region (64B rows),
// phys = L ^ ((row&7)<<4)  with row = L>>6, i.e. p4^=L6, p5^=L7, p6^=L8.
// Read side: frag offset ^= (lane&7)<<4. Stage side uses the inverse.
__device__ __forceinline__ int inv_swz(int p) {
  const int b6 = (p >> 6) & 1, b7 = (p >> 7) & 1, b8 = (p >> 8) & 1;
  return p ^ (((b6 ^ b8) << 4) | (b7 << 5) | (b8 << 6));
}

// ---------------- x fp32 -> bf16 ----------------
__global__ void cvtx_kernel(const float* __restrict__ x, unsigned short* __restrict__ xb) {
  const int i = blockIdx.x * blockDim.x + threadIdx.x;
  const float4 v = ((const float4*)x)[i];
  ushort4 o;
  o.x = f2b(v.x); o.y = f2b(v.y); o.z = f2b(v.z); o.w = f2b(v.w);
  ((ushort4*)xb)[i] = o;
}

// ---------------- gating: fp32 logits (experts 0..3), top-2, route ----------------
__global__ void gate_kernel(const float* __restrict__ x, const float* __restrict__ gw,
                            int* __restrict__ cnt, int* __restrict__ perm,
                            float* __restrict__ wgt, int* __restrict__ code) {
  const int lane = threadIdx.x & 63;
  const int wave = threadIdx.x >> 6;
  const int t = blockIdx.x * 4 + wave;          // one wave per token
  const float4* xv = (const float4*)(x + (size_t)t * DIM);
  const float4* g0 = (const float4*)gw;
  const float4* g1 = (const float4*)(gw + DIM);
  const float4* g2 = (const float4*)(gw + 2 * DIM);
  const float4* g3 = (const float4*)(gw + 3 * DIM);
  float a0 = 0.f, a1 = 0.f, a2 = 0.f, a3 = 0.f;
#pragma unroll
  for (int i = 0; i < 4; i++) {
    const int idx = i * 64 + lane;
    const float4 v = xv[idx];
    float4 w;
    w = g0[idx]; a0 += v.x*w.x + v.y*w.y + v.z*w.z + v.w*w.w;
    w = g1[idx]; a1 += v.x*w.x + v.y*w.y + v.z*w.z + v.w*w.w;
    w = g2[idx]; a2 += v.x*w.x + v.y*w.y + v.z*w.z + v.w*w.w;
    w = g3[idx]; a3 += v.x*w.x + v.y*w.y + v.z*w.z + v.w*w.w;
  }
#pragma unroll
  for (int off = 32; off > 0; off >>= 1) {
    a0 += __shfl_xor(a0, off);
    a1 += __shfl_xor(a1, off);
    a2 += __shfl_xor(a2, off);
    a3 += __shfl_xor(a3, off);
  }
  if (lane == 0) {
    float l[4] = {a0, a1, a2, a3};
    int a = 0;
#pragma unroll
    for (int e = 1; e < 4; e++) if (l[e] > l[a]) a = e;   // ties -> lower index (jax top_k)
    int b = (a == 0) ? 1 : 0;
#pragma unroll
    for (int e = 0; e < 4; e++) if (e != a && l[e] > l[b]) b = e;
    // softmax(top2) renormalized == sigmoid of logit gap
    const float wa = 1.0f / (1.0f + __expf(l[b] - l[a]));
    const float wb = 1.0f - wa;
    const int pa = atomicAdd(&cnt[a], 1);
    const int pb = atomicAdd(&cnt[b], 1);
    perm[a * T_TOK + pa] = t;  wgt[a * T_TOK + pa] = wa;  code[t * 2 + 0] = a * T_TOK + pa;
    perm[b * T_TOK + pb] = t;  wgt[b * T_TOK + pb] = wb;  code[t * 2 + 1] = b * T_TOK + pb;
  }
}

__global__ void offsets_kernel(const int* __restrict__ cnt, int* __restrict__ offs) {
  if (threadIdx.x == 0 && blockIdx.x == 0) {
    int s = 0;
#pragma unroll
    for (int e = 0; e < EA; e++) { offs[e] = s; s += cnt[e]; }
  }
}

// ---------------- per-expert transpose + fp32->bf16: in [R][C] -> out [C][R] ----------------
// 16B ushort8 stores: thread handles 2 chunks; chunk c -> out-row bc+(c>>3),
// k-offset (c&7)*8. LDS reads verified 2-way-free (bank stride 8, 65-pad).
__global__ void tcvt_kernel(const float* __restrict__ in, unsigned short* __restrict__ out,
                            int R, int C) {
  __shared__ float tile[64][65];
  const size_t es = (size_t)R * C;
  const float* ip = in + (size_t)blockIdx.z * es;
  unsigned short* op = out + (size_t)blockIdx.z * es;
  const int bc = blockIdx.x * 64;
  const int br = blockIdx.y * 64;
  const int tr = threadIdx.x >> 4;
  const int tc = (threadIdx.x & 15) * 4;
#pragma unroll
  for (int i = 0; i < 4; i++) {
    const float4 v = *(const float4*)(ip + (size_t)(br + tr + i * 16) * C + bc + tc);
    tile[tr + i * 16][tc + 0] = v.x;
    tile[tr + i * 16][tc + 1] = v.y;
    tile[tr + i * 16][tc + 2] = v.z;
    tile[tr + i * 16][tc + 3] = v.w;
  }
  __syncthreads();
#pragma unroll
  for (int h = 0; h < 2; h++) {
    const int c = h * 256 + threadIdx.x;   // chunk 0..511
    const int n = c >> 3;                  // out-row within tile
    const int koff = (c & 7) * 8;          // k within tile
    ushort8 o;
#pragma unroll
    for (int j = 0; j < 8; j++) o[j] = f2b(tile[koff + j][n]);
    *(ushort8*)(op + (size_t)(bc + n) * R + br + koff) = o;
  }
}

// ---------------- GEMM1: h = silu(x@w1) * (x@w3)  [R9 structure, 234us] ----------------
// Block 256M x 128N, 8 waves (4wm x 2wn), wave 64x64 per matrix, BK=64.
// LDS 2 bufs x 64KB: Ak0 16K@0 | Ak1 16K@16384 | B1k0 8K@32768 | B1k1 8K@40960
//                    | B3k0 8K@49152 | B3k1 8K@57344. 64B rows, XOR-swizzled.
// 4 phases/kt; counted vmcnt (vm4), never 0 mid-loop.
// Grid 2816: nb fastest (44), e (4), mb (16); same-(e,nb) stride 176 % 8 == 0.
__global__ __launch_bounds__(512, 2)
void gemm1_kernel(const unsigned short* __restrict__ xb,
                  const unsigned short* __restrict__ w1b,
                  const unsigned short* __restrict__ w3b,
                  unsigned short* __restrict__ hb,
                  const int* __restrict__ cnt, const int* __restrict__ offs,
                  const int* __restrict__ perm) {
  const int id = blockIdx.x;
  const int nb = id % 44;
  const int e  = (id / 44) % 4;
  const int mb = id / 176;              // 0..15
  const int Me = cnt[e];
  const int m0 = mb * 256;
  if (m0 >= Me) return;
  const int n0 = nb * 128;
  const int goff = offs[e];
  const int tid = threadIdx.x, lane = tid & 63, wave = tid >> 6;
  const int wm = wave >> 1, wn = wave & 1;
  const int fm = lane & 15;

  __shared__ __align__(16) char smem[2 * 65536];

  const int t16 = tid * 16;
  const int l0 = inv_swz(t16);
  const int srow = l0 >> 6;             // 0..127
  const int ks   = (l0 & 63) >> 1;      // shorts within 32-short k-slice
  const int tok0 = perm[e * T_TOK + min(m0 + srow, Me - 1)];
  const int tok1 = perm[e * T_TOK + min(m0 + 128 + srow, Me - 1)];
  const unsigned short* ap0 = xb + (size_t)tok0 * DIM + ks;
  const unsigned short* ap1 = xb + (size_t)tok1 * DIM + ks;
  const unsigned short* b1p = w1b + ((size_t)e * HID + n0 + srow) * DIM + ks;
  const unsigned short* b3p = w3b + ((size_t)e * HID + n0 + srow) * DIM + ks;

  const int dA0 = wave * 1024;                 // Ak0 batch0; batch1 +8192; Ak1 +16384
  const int dA1 = 8192  + wave * 1024;
  const int dB1 = 32768 + wave * 1024;         // B1k0; B1k1 +8192
  const int dB3 = 49152 + wave * 1024;         // B3k0; B3k1 +8192

  const int X = (lane & 7) << 4;
  const int aoff = (((wm * 64 + fm) * 64) + ((lane >> 4) * 16)) ^ X;
  const int boff = (((wn * 64 + fm) * 64) + ((lane >> 4) * 16)) ^ X;

  f32x4 acc1[4][4] = {};
  f32x4 acc3[4][4] = {};

  // prologue: stage kt0 h0+h1 into buf0 (8 loads/thread in flight)
  {
    char* D = smem;
    async16(ap0, D + dA0);            async16(ap1, D + dA1);
    async16(b1p, D + dB1);            async16(b3p, D + dB3);
    async16(ap0 + 32, D + dA0 + 16384); async16(ap1 + 32, D + dA1 + 16384);
    async16(b1p + 32, D + dB1 + 8192);  async16(b3p + 32, D + dB3 + 8192);
    ap0 += 64; ap1 += 64; b1p += 64; b3p += 64;
  }
  wait_vm4();               // kt0 h0 landed; h1 (4 loads) still in flight
  bar_raw();

  for (int kt = 0; kt < NT1; ++kt) {
    const char* S = smem + (kt & 1) * 65536;
    char* D = smem + ((kt + 1) & 1) * 65536;
    const bool nl = (kt < NT1 - 1);
    bf16x8 af[4], bfr[4];
    // ===== ph0: read Ak0 + B1k0, stage kt+1 A-k0, MFMA acc1 =====
#pragma unroll
    for (int mi = 0; mi < 4; mi++)
      af[mi] = *(const bf16x8*)(S + aoff + mi * 1024);
#pragma unroll
    for (int ni = 0; ni < 4; ni++)
      bfr[ni] = *(const bf16x8*)(S + 32768 + boff + ni * 1024);
    if (nl) { async16(ap0, D + dA0); async16(ap1, D + dA1); }
    bar_raw(); wait_lgkm0();
    __builtin_amdgcn_s_setprio(1);
#pragma unroll
    for (int mi = 0; mi < 4; mi++)
#pragma unroll
      for (int ni = 0; ni < 4; ni++)
        acc1[mi][ni] = __builtin_amdgcn_mfma_f32_16x16x32_bf16(af[mi], bfr[ni], acc1[mi][ni], 0, 0, 0);
    __builtin_amdgcn_s_setprio(0);
    bar_raw();
    // ===== ph1: read B3k0 (A regs reused), stage kt+1 B-k0, vm4, MFMA acc3 =====
#pragma unroll
    for (int ni = 0; ni < 4; ni++)
      bfr[ni] = *(const bf16x8*)(S + 49152 + boff + ni * 1024);
    if (nl) { async16(b1p, D + dB1); async16(b3p, D + dB3); wait_vm4(); }
    else    { wait_vm0(); }
    bar_raw(); wait_lgkm0();
    __builtin_amdgcn_s_setprio(1);
#pragma unroll
    for (int mi = 0; mi < 4; mi++)
#pragma unroll
      for (int ni = 0; ni < 4; ni++)
        acc3[mi][ni] = __builtin_amdgcn_mfma_f32_16x16x32_bf16(af[mi], bfr[ni], acc3[mi][ni], 0, 0, 0);
    __builtin_amdgcn_s_setprio(0);
    bar_raw();
    // ===== ph2: read Ak1 + B1k1, stage kt+1 A-k1, MFMA acc1 =====
#pragma unroll
    for (int mi = 0; mi < 4; mi++)
      af[mi] = *(const bf16x8*)(S + 16384 + aoff + mi * 1024);
#pragma unroll
    for (int ni = 0; ni < 4; ni++)
      bfr[ni] = *(const bf16x8*)(S + 40960 + boff + ni * 1024);
    if (nl) { async16(ap0 + 32, D + dA0 + 16384); async16(ap1 + 32, D + dA1 + 16384); }
    bar_raw(); wait_lgkm0();
    __builtin_amdgcn_s_setprio(1);
#pragma unroll
    for (int mi = 0; mi < 4; mi++)
#pragma unroll
      for (int ni = 0; ni < 4; ni++)
        acc1[mi][ni] = __builtin_amdgcn_mfma_f32_16x16x32_bf16(af[mi], bfr[ni], acc1[mi][ni], 0, 0, 0);
    __builtin_amdgcn_s_setprio(0);
    bar_raw();
    // ===== ph3: read B3k1, stage kt+1 B-k1, vm4, MFMA acc3 =====
#pragma unroll
    for (int ni = 0; ni < 4; ni++)
      bfr[ni] = *(const bf16x8*)(S + 57344 + boff + ni * 1024);
    if (nl) {
      async16(b1p + 32, D + dB1 + 8192); async16(b3p + 32, D + dB3 + 8192);
      ap0 += 64; ap1 += 64; b1p += 64; b3p += 64;
      wait_vm4();
    } else { wait_vm0(); }
    bar_raw(); wait_lgkm0();
    __builtin_amdgcn_s_setprio(1);
#pragma unroll
    for (int mi = 0; mi < 4; mi++)
#pragma unroll
      for (int ni = 0; ni < 4; ni++)
        acc3[mi][ni] = __builtin_amdgcn_mfma_f32_16x16x32_bf16(af[mi], bfr[ni], acc3[mi][ni], 0, 0, 0);
    __builtin_amdgcn_s_setprio(0);
    bar_raw();
  }

  // epilogue: SwiGLU, masked store (C/D layout: col=lane&15, row=(lane>>4)*4+reg)
#pragma unroll
  for (int mi = 0; mi < 4; mi++) {
#pragma unroll
    for (int r = 0; r < 4; r++) {
      const int m = m0 + wm * 64 + mi * 16 + (lane >> 4) * 4 + r;
      if (m < Me) {
        unsigned short* hp = hb + (size_t)(goff + m) * HID + n0 + wn * 64 + fm;
#pragma unroll
        for (int ni = 0; ni < 4; ni++) {
          const float a = acc1[mi][ni][r];
          const float g = acc3[mi][ni][r];
          hp[ni * 16] = f2b((a / (1.0f + __expf(-a))) * g);
        }
      }
    }
  }
}

// ---------------- GEMM2: y = (h @ w2) * gate_w  [R6 structure, in 945.8us run] ----------------
// Tile 128M x 128N, BK=32, 4 waves (2M x 2N), per-wave 64x64.
// Triple-buffered LDS: buf = [A 8KB | B 8KB] = 16KB, x3 = 48KB -> 3 blocks/CU.
// One barrier per K-tile; counted vmcnt(4).
// Grid 1024: nb fastest (8), e (4), mb (32); same-(e,nb) stride 32 % 8 == 0.
__global__ __launch_bounds__(256, 3)
void gemm2_kernel(const unsigned short* __restrict__ hb,
                  const unsigned short* __restrict__ w2b,
                  unsigned short* __restrict__ yb,
                  const int* __restrict__ cnt, const int* __restrict__ offs,
                  const float* __restrict__ wgt) {
  const int id = blockIdx.x;
  const int nb = id & 7;
  const int e  = (id >> 3) & 3;
  const int mb = id >> 5;               // 0..31
  const int Me = cnt[e];
  const int m0 = mb * 128;
  if (m0 >= Me) return;
  const int n0 = nb * 128;
  const int goff = offs[e];
  const int tid = threadIdx.x, lane = tid & 63, wave = tid >> 6;
  const int wm = wave >> 1, wn = wave & 1;
  const int fm = lane & 15;

  __shared__ __align__(16) char smem[3 * 16384];

  const int t16 = tid * 16;
  const int l0 = inv_swz(t16);
  const int row0 = l0 >> 6;
  const int row1 = row0 + 64;
  const int ks   = (l0 & 63) >> 1;
  const unsigned short* ap0 = hb + (size_t)(goff + min(m0 + row0, Me - 1)) * HID + ks;
  const unsigned short* ap1 = hb + (size_t)(goff + min(m0 + row1, Me - 1)) * HID + ks;
  const unsigned short* bp0 = w2b + ((size_t)e * DIM + n0 + row0) * HID + ks;
  const unsigned short* bp1 = w2b + ((size_t)e * DIM + n0 + row1) * HID + ks;

  const int dA0 = wave * 1024,         dA1 = 4096  + wave * 1024;
  const int dB0 = 8192 + wave * 1024,  dB1 = 12288 + wave * 1024;

  const int X = (lane & 7) << 4;
  const int aoff = (((wm * 64 + fm) * 64) + ((lane >> 4) * 16)) ^ X;
  const int boff = (((wn * 64 + fm) * 64) + ((lane >> 4) * 16)) ^ X;

  f32x4 acc[4][4] = {};

#define G2_STAGE(D) do { \
    async16(ap0, (D) + dA0); async16(ap1, (D) + dA1); \
    async16(bp0, (D) + dB0); async16(bp1, (D) + dB1); \
    ap0 += 32; ap1 += 32; bp0 += 32; bp1 += 32; \
  } while (0)

  G2_STAGE(smem);
  G2_STAGE(smem + 16384);
  wait_vm4();               // kt0 landed; kt1 (4 loads) in flight
  bar_raw();

  int cb = 0, sb = 2;
  for (int kt = 0; kt < NT2G; ++kt) {
    const char* S = smem + cb * 16384;
    char* D = smem + sb * 16384;
    bf16x8 af[4], bfr[4];
#pragma unroll
    for (int mi = 0; mi < 4; mi++)
      af[mi] = *(const bf16x8*)(S + aoff + mi * 1024);
#pragma unroll
    for (int ni = 0; ni < 4; ni++)
      bfr[ni] = *(const bf16x8*)(S + 8192 + boff + ni * 1024);
    if (kt < NT2G - 2) G2_STAGE(D);
    wait_lgkm0();
    __builtin_amdgcn_s_setprio(1);
#pragma unroll
    for (int mi = 0; mi < 4; mi++)
#pragma unroll
      for (int ni = 0; ni < 4; ni++)
        acc[mi][ni] = __builtin_amdgcn_mfma_f32_16x16x32_bf16(af[mi], bfr[ni], acc[mi][ni], 0, 0, 0);
    __builtin_amdgcn_s_setprio(0);
    if (kt < NT2G - 2) wait_vm4(); else wait_vm0();
    bar_raw();
    cb = (cb == 2) ? 0 : cb + 1;
    sb = (sb == 2) ? 0 : sb + 1;
  }
#undef G2_STAGE

#pragma unroll
  for (int mi = 0; mi < 4; mi++) {
#pragma unroll
    for (int r = 0; r < 4; r++) {
      const int m = m0 + wm * 64 + mi * 16 + (lane >> 4) * 4 + r;
      if (m < Me) {
        const float gwv = wgt[e * T_TOK + m];
        unsigned short* yp = yb + (size_t)(goff + m) * DIM + n0 + wn * 64 + fm;
#pragma unroll
        for (int ni = 0; ni < 4; ni++)
          yp[ni * 16] = f2b(acc[mi][ni][r] * gwv);
      }
    }
  }
}

// ---------------- combine: out[t] = y[slot0(t)] + y[slot1(t)] ----------------
__global__ void combine_kernel(const unsigned short* __restrict__ yb,
                               const int* __restrict__ code,
                               const int* __restrict__ offs,
                               float* __restrict__ out) {
  const int t = blockIdx.x;
  const int d = threadIdx.x * 4;
  const int c0 = code[t * 2 + 0];
  const int c1 = code[t * 2 + 1];
  const size_t g0 = ((size_t)(offs[c0 >> 12] + (c0 & 4095))) * DIM + d;
  const size_t g1 = ((size_t)(offs[c1 >> 12] + (c1 & 4095))) * DIM + d;
  const ushort4 y0 = *(const ushort4*)(yb + g0);
  const ushort4 y1 = *(const ushort4*)(yb + g1);
  float4 o;
  o.x = b2f(y0.x) + b2f(y1.x);
  o.y = b2f(y0.y) + b2f(y1.y);
  o.z = b2f(y0.z) + b2f(y1.z);
  o.w = b2f(y0.w) + b2f(y1.w);
  *(float4*)(out + (size_t)t * DIM + d) = o;
}

extern "C" void kernel_launch(void* const* d_in, const int* in_sizes, int n_in,
                              void* d_out, int out_size, void* d_ws, size_t ws_size,
                              hipStream_t stream) {
  (void)in_sizes; (void)n_in; (void)out_size; (void)ws_size;
  const float* x  = (const float*)d_in[0];
  const float* gw = (const float*)d_in[1];
  const float* w1 = (const float*)d_in[2];   // [E][D][H]
  const float* w2 = (const float*)d_in[3];   // [E][H][D]  (dict order: w2 before w3!)
  const float* w3 = (const float*)d_in[4];   // [E][D][H]
  float* out = (float*)d_out;
  char* ws = (char*)d_ws;

  unsigned short* xb  = (unsigned short*)(ws + 0);
  unsigned short* w1b = (unsigned short*)(ws + 8388608);
  unsigned short* yb  = (unsigned short*)(ws + 8388608);    // aliases w1b (dead after gemm1)
  unsigned short* w3b = (unsigned short*)(ws + 54525952);
  unsigned short* w2b = (unsigned short*)(ws + 100663296);
  unsigned short* hb  = (unsigned short*)(ws + 146800640);  // 8320 rows x 5632 bf16 (128 pad rows)
  int*   cnt  = (int*)(ws + 240517120);
  int*   offs = (int*)(ws + 240517152);
  int*   perm = (int*)(ws + 240517184);
  float* wgt  = (float*)(ws + 240582720);
  int*   code = (int*)(ws + 240648256);

  hipMemsetAsync(cnt, 0, EA * sizeof(int), stream);
  cvtx_kernel<<<4096, 256, 0, stream>>>(x, xb);
  gate_kernel<<<1024, 256, 0, stream>>>(x, gw, cnt, perm, wgt, code);
  offsets_kernel<<<1, 64, 0, stream>>>(cnt, offs);
  tcvt_kernel<<<dim3(88, 16, EA), 256, 0, stream>>>(w1, w1b, DIM, HID);  // -> [e][H][D]
  tcvt_kernel<<<dim3(88, 16, EA), 256, 0, stream>>>(w3, w3b, DIM, HID);  // -> [e][H][D]
  tcvt_kernel<<<dim3(16, 88, EA), 256, 0, stream>>>(w2, w2b, HID, DIM);  // -> [e][D][H]
  gemm1_kernel<<<2816, 512, 0, stream>>>(xb, w1b, w3b, hb, cnt, offs, perm);
  gemm2_kernel<<<1024, 256, 0, stream>>>(hb, w2b, yb, cnt, offs, wgt);
  combine_kernel<<<4096, 256, 0, stream>>>(yb, code, offs, out);
}